// Round 4
// baseline (585.363 us; speedup 1.0000x reference)
//
#include <hip/hip_runtime.h>
#include <hip/hip_bf16.h>
#include <stdint.h>

typedef __bf16 bf16x8 __attribute__((ext_vector_type(8)));
typedef float f32x4 __attribute__((ext_vector_type(4)));

#define T_SEQ 4096
#define C_DIM 1024
#define H_NUM 16
#define HD 64
#define C3 3072
#define NEG_BIG (-30000.0f)

__device__ __forceinline__ unsigned short f2bf(float f) {
    uint32_t u = __builtin_bit_cast(uint32_t, f);
    u += 0x7fffu + ((u >> 16) & 1u);
    return (unsigned short)(u >> 16);
}

__device__ __forceinline__ bf16x8 ld_bf8(const unsigned short* p) {
    return *reinterpret_cast<const bf16x8*>(p);
}

__device__ __forceinline__ void async_g2l16(const unsigned short* g, unsigned short* l) {
    __builtin_amdgcn_global_load_lds(
        (const __attribute__((address_space(1))) void*)g,
        (__attribute__((address_space(3))) void*)l, 16, 0, 0);
}

__device__ __forceinline__ void store_c(unsigned short* C, size_t idx, float v) { C[idx] = f2bf(v); }
__device__ __forceinline__ void store_c(float* C, size_t idx, float v)          { C[idx] = v; }

// fp32 -> bf16 elementwise convert, 8 elems/thread
__global__ void cvt_f32_bf16(const float* __restrict__ src, unsigned short* __restrict__ dst, int n) {
    int i = (blockIdx.x * blockDim.x + threadIdx.x) * 8;
    if (i >= n) return;
    float4 f0 = *(const float4*)(src + i);
    float4 f1 = *(const float4*)(src + i + 4);
    union { unsigned short u[8]; uint4 q; } t;
    t.u[0] = f2bf(f0.x); t.u[1] = f2bf(f0.y); t.u[2] = f2bf(f0.z); t.u[3] = f2bf(f0.w);
    t.u[4] = f2bf(f1.x); t.u[5] = f2bf(f1.y); t.u[6] = f2bf(f1.z); t.u[7] = f2bf(f1.w);
    *(uint4*)(dst + i) = t.q;
}

// C = A @ B^T, bf16 inputs, m97-style async staging. 128x128 tile, BK=32.
// If Vt != null, blocks with n0 >= 2048 also scatter C^T into Vt[col-2048][row]
// (transposed V for the flash kernel; rows of 4 packed as 8B stores).
template <typename TC>
__global__ __launch_bounds__(256, 2) void gemm_bt(
    const unsigned short* __restrict__ A, const unsigned short* __restrict__ B,
    TC* __restrict__ C, unsigned short* __restrict__ Vt, int M, int N, int K)
{
    __shared__ __attribute__((aligned(16))) unsigned short As[128 * 32];
    __shared__ __attribute__((aligned(16))) unsigned short Bs[128 * 32];

    const int tid  = threadIdx.x;
    const int wave = tid >> 6, lane = tid & 63;
    const int quad = lane >> 4, l16 = lane & 15;
    const int wm = wave >> 1, wn = wave & 1;
    const int m0 = blockIdx.y * 128, n0 = blockIdx.x * 128;

    const int srow = wave * 32 + (lane >> 2);
    const int scol = (lane & 3) * 8;

    f32x4 acc[4][4] = {};

    for (int k0 = 0; k0 < K; k0 += 32) {
        {
            const unsigned short* ga = A + (size_t)(m0 + srow) * K + k0 + scol;
            const unsigned short* gb = B + (size_t)(n0 + srow) * K + k0 + scol;
            unsigned short* la = As + (wave * 32) * 32;
            unsigned short* lb = Bs + (wave * 32) * 32;
            async_g2l16(ga, la);
            async_g2l16(ga + (size_t)16 * K, la + 16 * 32);
            async_g2l16(gb, lb);
            async_g2l16(gb + (size_t)16 * K, lb + 16 * 32);
        }
        __syncthreads();

        bf16x8 af[4], bf[4];
        #pragma unroll
        for (int i = 0; i < 4; ++i) {
            af[i] = ld_bf8(As + (wm * 64 + i * 16 + l16) * 32 + quad * 8);
            bf[i] = ld_bf8(Bs + (wn * 64 + i * 16 + l16) * 32 + quad * 8);
        }
        #pragma unroll
        for (int mt = 0; mt < 4; ++mt)
            #pragma unroll
            for (int nt = 0; nt < 4; ++nt)
                acc[mt][nt] = __builtin_amdgcn_mfma_f32_16x16x32_bf16(
                    af[mt], bf[nt], acc[mt][nt], 0, 0, 0);
        __syncthreads();
    }

    #pragma unroll
    for (int mt = 0; mt < 4; ++mt)
        #pragma unroll
        for (int nt = 0; nt < 4; ++nt)
            #pragma unroll
            for (int r = 0; r < 4; ++r) {
                int row = m0 + wm * 64 + mt * 16 + quad * 4 + r;
                int col = n0 + wn * 64 + nt * 16 + l16;
                store_c(C, (size_t)row * N + col, acc[mt][nt][r]);
            }

    if (Vt != nullptr && n0 >= 2048) {           // block-uniform branch
        #pragma unroll
        for (int mt = 0; mt < 4; ++mt)
            #pragma unroll
            for (int nt = 0; nt < 4; ++nt) {
                int col = n0 + wn * 64 + nt * 16 + l16 - 2048;
                int row = m0 + wm * 64 + mt * 16 + quad * 4;
                union { unsigned short u[4]; uint2 q; } t;
                #pragma unroll
                for (int r = 0; r < 4; ++r) t.u[r] = f2bf(acc[mt][nt][r]);
                *(uint2*)(Vt + (size_t)col * T_SEQ + row) = t.q;
            }
    }
}

// Flash attention v2: S^T = K Q^T, O^T = V^T P^T. Barrier-free (wave-private
// P buffer); per-wave exact causal trip count; big q-blocks launched first.
__global__ __launch_bounds__(256, 4) void flash_attn2(
    const unsigned short* __restrict__ qkv,
    const unsigned short* __restrict__ Vt,
    unsigned short* __restrict__ Y)
{
    __shared__ __attribute__((aligned(16))) unsigned short Pl[4][16 * 32];

    const int tid  = threadIdx.x;
    const int wave = tid >> 6, lane = tid & 63;
    const int quad = lane >> 4, l16 = lane & 15;
    const int h  = blockIdx.y;
    const int qb = 63 - blockIdx.x;                 // descending size order
    const int q0 = qb * 64 + wave * 16;

    bf16x8 qf[2];
    {
        const unsigned short* qp = qkv + (size_t)(q0 + l16) * C3 + h * HD + quad * 8;
        qf[0] = ld_bf8(qp);
        qf[1] = ld_bf8(qp + 32);
    }

    f32x4 o[4] = {};
    float m_s = NEG_BIG, l_s = 0.f;
    const int q_abs = q0 + l16;
    const int nkt = (q0 + 47) >> 5;                 // ceil((q0+16)/32)

    unsigned short* pbuf = Pl[wave];
    const int swz = 8 * (l16 & 3);
    const unsigned short* vbase = Vt + (size_t)(h * HD + l16) * T_SEQ;

    for (int kt = 0; kt < nkt; ++kt) {
        const int k0 = kt * 32;

        // prefetch V^T fragments early (L2-latency overlap with softmax)
        bf16x8 vt[4];
        #pragma unroll
        for (int c = 0; c < 4; ++c)
            vt[c] = ld_bf8(vbase + (size_t)(c * 16) * T_SEQ + k0 + quad * 8);

        // S^T = K Q^T : rows=keys (quad*4+r + s*16), cols=q (l16)
        f32x4 st[2] = {};
        #pragma unroll
        for (int s = 0; s < 2; ++s) {
            const unsigned short* kp =
                qkv + (size_t)(k0 + s * 16 + l16) * C3 + C_DIM + h * HD + quad * 8;
            st[s] = __builtin_amdgcn_mfma_f32_16x16x32_bf16(ld_bf8(kp),      qf[0], st[s], 0, 0, 0);
            st[s] = __builtin_amdgcn_mfma_f32_16x16x32_bf16(ld_bf8(kp + 32), qf[1], st[s], 0, 0, 0);
        }

        // mask + scale; per-lane max over 8 values then 2 cross-quad shuffles
        float p[8];
        float tm = NEG_BIG;
        #pragma unroll
        for (int s = 0; s < 2; ++s)
            #pragma unroll
            for (int r = 0; r < 4; ++r) {
                int key = k0 + s * 16 + quad * 4 + r;
                float v = st[s][r] * 0.125f;
                v = (key <= q_abs) ? v : NEG_BIG;
                p[s * 4 + r] = v;
                tm = fmaxf(tm, v);
            }
        tm = fmaxf(tm, __shfl_xor(tm, 16, 64));
        tm = fmaxf(tm, __shfl_xor(tm, 32, 64));
        float mn    = fmaxf(m_s, tm);
        float alpha = __expf(m_s - mn);
        float ts = 0.f;
        #pragma unroll
        for (int i = 0; i < 8; ++i) { p[i] = __expf(p[i] - mn); ts += p[i]; }
        ts += __shfl_xor(ts, 16, 64);
        ts += __shfl_xor(ts, 32, 64);
        m_s = mn;
        l_s = l_s * alpha + ts;
        #pragma unroll
        for (int c = 0; c < 4; ++c)
            #pragma unroll
            for (int r = 0; r < 4; ++r) o[c][r] *= alpha;

        // P^T -> wave-private LDS [q][key ^ swz] (xor swizzle spreads banks)
        #pragma unroll
        for (int s = 0; s < 2; ++s)
            #pragma unroll
            for (int rp = 0; rp < 4; rp += 2) {
                int key = s * 16 + quad * 4 + rp;
                uint32_t pk = (uint32_t)f2bf(p[s * 4 + rp]) |
                              ((uint32_t)f2bf(p[s * 4 + rp + 1]) << 16);
                *(uint32_t*)(pbuf + l16 * 32 + (key ^ swz)) = pk;
            }
        bf16x8 pf = ld_bf8(pbuf + l16 * 32 + ((quad * 8) ^ swz));

        // O^T += V^T P^T
        #pragma unroll
        for (int c = 0; c < 4; ++c)
            o[c] = __builtin_amdgcn_mfma_f32_16x16x32_bf16(vt[c], pf, o[c], 0, 0, 0);
    }

    // epilogue: O^T C-layout row=ch=quad*4+r (+c*16), col=q=l16
    float inv_l = 1.f / l_s;
    #pragma unroll
    for (int c = 0; c < 4; ++c) {
        union { unsigned short u[4]; uint2 q; } t;
        #pragma unroll
        for (int r = 0; r < 4; ++r) t.u[r] = f2bf(o[c][r] * inv_l);
        *(uint2*)(Y + (size_t)q_abs * C_DIM + h * HD + c * 16 + quad * 4) = t.q;
    }
}

extern "C" void kernel_launch(void* const* d_in, const int* in_sizes, int n_in,
                              void* d_out, int out_size, void* d_ws, size_t ws_size,
                              hipStream_t stream) {
    const float* x      = (const float*)d_in[0];   // [4096,1024] fp32
    const float* w_attn = (const float*)d_in[1];   // [3072,1024] fp32
    const float* w_proj = (const float*)d_in[2];   // [1024,1024] fp32
    float* out = (float*)d_out;                    // [4096,1024] fp32 (16 MB)

    // ws layout (32 MB, same footprint as round 3):
    //   [0, 24MB)  : qkv bf16 [4096,3072]   (dead after flash; wpb reuses base)
    //   [24, 32MB) : xb bf16 [4096,1024], then y bf16 (xb dead after gemm1)
    unsigned short* qkv = (unsigned short*)d_ws;
    unsigned short* xb  = qkv + (size_t)T_SEQ * C3;
    unsigned short* y   = xb;                       // alias: xb dead after gemm1
    unsigned short* wpb = qkv;                      // alias: qkv dead after flash
    // d_out scratch (dead until gemm2): [0,8MB) Vt bf16 [1024][4096]; [8,14MB) wab
    unsigned short* Vt  = (unsigned short*)d_out;
    unsigned short* wab = Vt + (size_t)C_DIM * T_SEQ;

    // fp32 -> bf16 converts
    cvt_f32_bf16<<<(T_SEQ * C_DIM / 8 + 255) / 256, 256, 0, stream>>>(x, xb, T_SEQ * C_DIM);
    cvt_f32_bf16<<<(C3 * C_DIM / 8 + 255) / 256, 256, 0, stream>>>(w_attn, wab, C3 * C_DIM);

    // qkv = xb @ wab^T  (+ transposed V scatter into Vt)
    gemm_bt<unsigned short>
        <<<dim3(C3 / 128, T_SEQ / 128), 256, 0, stream>>>(xb, wab, qkv, Vt, T_SEQ, C3, C_DIM);

    // y = attention(qkv, Vt)
    flash_attn2<<<dim3(T_SEQ / 64, H_NUM), 256, 0, stream>>>(qkv, Vt, y);

    // w_proj -> bf16 (qkv region now dead), then out = y @ wpb^T (fp32 out)
    cvt_f32_bf16<<<(C_DIM * C_DIM / 8 + 255) / 256, 256, 0, stream>>>(w_proj, wpb, C_DIM * C_DIM);
    gemm_bt<float>
        <<<dim3(C_DIM / 128, T_SEQ / 128), 256, 0, stream>>>(y, wpb, out, nullptr, T_SEQ, C_DIM, C_DIM);
}

// Round 5
// 292.146 us; speedup vs baseline: 2.0037x; 2.0037x over previous
//
#include <hip/hip_runtime.h>
#include <hip/hip_bf16.h>
#include <stdint.h>

typedef __bf16 bf16x8 __attribute__((ext_vector_type(8)));
typedef float f32x4 __attribute__((ext_vector_type(4)));

#define T_SEQ 4096
#define C_DIM 1024
#define H_NUM 16
#define HD 64
#define C3 3072
#define NEG_BIG (-30000.0f)

__device__ __forceinline__ unsigned short f2bf(float f) {
    uint32_t u = __builtin_bit_cast(uint32_t, f);
    u += 0x7fffu + ((u >> 16) & 1u);
    return (unsigned short)(u >> 16);
}

__device__ __forceinline__ bf16x8 ld_bf8(const unsigned short* p) {
    return *reinterpret_cast<const bf16x8*>(p);
}

__device__ __forceinline__ void async_g2l16(const unsigned short* g, unsigned short* l) {
    __builtin_amdgcn_global_load_lds(
        (const __attribute__((address_space(1))) void*)g,
        (__attribute__((address_space(3))) void*)l, 16, 0, 0);
}

__device__ __forceinline__ void store_c(unsigned short* C, size_t idx, float v) { C[idx] = f2bf(v); }
__device__ __forceinline__ void store_c(float* C, size_t idx, float v)          { C[idx] = v; }

// fp32 -> bf16 elementwise convert, 8 elems/thread
__global__ void cvt_f32_bf16(const float* __restrict__ src, unsigned short* __restrict__ dst, int n) {
    int i = (blockIdx.x * blockDim.x + threadIdx.x) * 8;
    if (i >= n) return;
    float4 f0 = *(const float4*)(src + i);
    float4 f1 = *(const float4*)(src + i + 4);
    union { unsigned short u[8]; uint4 q; } t;
    t.u[0] = f2bf(f0.x); t.u[1] = f2bf(f0.y); t.u[2] = f2bf(f0.z); t.u[3] = f2bf(f0.w);
    t.u[4] = f2bf(f1.x); t.u[5] = f2bf(f1.y); t.u[6] = f2bf(f1.z); t.u[7] = f2bf(f1.w);
    *(uint4*)(dst + i) = t.q;
}

// C = A @ B^T, bf16, m97 async staging. 128x128 tile, BK=32. Optional Vt scatter.
template <typename TC>
__global__ __launch_bounds__(256, 2) void gemm_bt(
    const unsigned short* __restrict__ A, const unsigned short* __restrict__ B,
    TC* __restrict__ C, unsigned short* __restrict__ Vt, int M, int N, int K)
{
    __shared__ __attribute__((aligned(16))) unsigned short As[128 * 32];
    __shared__ __attribute__((aligned(16))) unsigned short Bs[128 * 32];

    const int tid  = threadIdx.x;
    const int wave = tid >> 6, lane = tid & 63;
    const int quad = lane >> 4, l16 = lane & 15;
    const int wm = wave >> 1, wn = wave & 1;
    const int m0 = blockIdx.y * 128, n0 = blockIdx.x * 128;

    const int srow = wave * 32 + (lane >> 2);
    const int scol = (lane & 3) * 8;

    f32x4 acc[4][4] = {};

    for (int k0 = 0; k0 < K; k0 += 32) {
        {
            const unsigned short* ga = A + (size_t)(m0 + srow) * K + k0 + scol;
            const unsigned short* gb = B + (size_t)(n0 + srow) * K + k0 + scol;
            unsigned short* la = As + (wave * 32) * 32;
            unsigned short* lb = Bs + (wave * 32) * 32;
            async_g2l16(ga, la);
            async_g2l16(ga + (size_t)16 * K, la + 16 * 32);
            async_g2l16(gb, lb);
            async_g2l16(gb + (size_t)16 * K, lb + 16 * 32);
        }
        __syncthreads();

        bf16x8 af[4], bf[4];
        #pragma unroll
        for (int i = 0; i < 4; ++i) {
            af[i] = ld_bf8(As + (wm * 64 + i * 16 + l16) * 32 + quad * 8);
            bf[i] = ld_bf8(Bs + (wn * 64 + i * 16 + l16) * 32 + quad * 8);
        }
        #pragma unroll
        for (int mt = 0; mt < 4; ++mt)
            #pragma unroll
            for (int nt = 0; nt < 4; ++nt)
                acc[mt][nt] = __builtin_amdgcn_mfma_f32_16x16x32_bf16(
                    af[mt], bf[nt], acc[mt][nt], 0, 0, 0);
        __syncthreads();
    }

    #pragma unroll
    for (int mt = 0; mt < 4; ++mt)
        #pragma unroll
        for (int nt = 0; nt < 4; ++nt)
            #pragma unroll
            for (int r = 0; r < 4; ++r) {
                int row = m0 + wm * 64 + mt * 16 + quad * 4 + r;
                int col = n0 + wn * 64 + nt * 16 + l16;
                store_c(C, (size_t)row * N + col, acc[mt][nt][r]);
            }

    if (Vt != nullptr && n0 >= 2048) {
        #pragma unroll
        for (int mt = 0; mt < 4; ++mt)
            #pragma unroll
            for (int nt = 0; nt < 4; ++nt) {
                int col = n0 + wn * 64 + nt * 16 + l16 - 2048;
                int row = m0 + wm * 64 + mt * 16 + quad * 4;
                union { unsigned short u[4]; uint2 q; } t;
                #pragma unroll
                for (int r = 0; r < 4; ++r) t.u[r] = f2bf(acc[mt][nt][r]);
                *(uint2*)(Vt + (size_t)col * T_SEQ + row) = t.q;
            }
    }
}

// Flash attention v3: block = (head, 64 q-rows), 4 waves. Per 64-key tile, the
// block cooperatively stages K[64x64] and V^T[64x64] into LDS (coalesced
// global_load_lds, XOR chunk swizzle on the global side so ds_read_b128
// fragment reads are conflict-free). S^T = K Q^T, O^T = V^T P^T.
__global__ __launch_bounds__(256, 4) void flash_attn3(
    const unsigned short* __restrict__ qkv,
    const unsigned short* __restrict__ Vt,
    unsigned short* __restrict__ Y)
{
    __shared__ __attribute__((aligned(16))) unsigned short Ks[64 * 64];
    __shared__ __attribute__((aligned(16))) unsigned short Vs[64 * 64];
    __shared__ __attribute__((aligned(16))) unsigned short Pl[4][16 * 64];

    const int tid  = threadIdx.x;
    const int wave = tid >> 6, lane = tid & 63;
    const int quad = lane >> 4, l16 = lane & 15;
    const int h  = blockIdx.y;
    const int qb = 63 - blockIdx.x;                 // big blocks first
    const int q0w = qb * 64 + wave * 16;
    const int q_abs = q0w + l16;

    // Q fragments (B-operand: n=l16 -> q row, k=quad*8+j -> channel)
    bf16x8 qf[2];
    {
        const unsigned short* qp = qkv + (size_t)(q0w + l16) * C3 + h * HD + quad * 8;
        qf[0] = ld_bf8(qp);
        qf[1] = ld_bf8(qp + 32);
    }

    f32x4 o[4] = {};
    float m_s = NEG_BIG, l_s = 0.f;

    unsigned short* pbuf = Pl[wave];
    const int sw = l16 & 7;                          // pbuf/fragment swizzle key

    // staging lane map: row-in-group = lane/8, chunk = lane%8 (forced by HW)
    const int srow = lane >> 3;                      // 0..7
    const int schunk = (lane & 7) ^ (lane >> 3);     // XOR swizzle, global side

    const int ntiles = qb + 1;
    for (int t = 0; t < ntiles; ++t) {
        const int k0 = t * 64;

        // ---- cooperative staging: K rows & V^T rows, 2+2 calls per wave ----
        #pragma unroll
        for (int j = 0; j < 2; ++j) {
            int row0 = wave * 16 + j * 8;            // 8-row group
            int row  = row0 + srow;
            const unsigned short* gk =
                qkv + (size_t)(k0 + row) * C3 + C_DIM + h * HD + schunk * 8;
            const unsigned short* gv =
                Vt + (size_t)(h * HD + row) * T_SEQ + k0 + schunk * 8;
            async_g2l16(gk, Ks + row0 * 64);
            async_g2l16(gv, Vs + row0 * 64);
        }
        __syncthreads();

        // ---- S^T = K Q^T : 4 key-subtiles of 16 ----
        f32x4 st[4];
        #pragma unroll
        for (int s = 0; s < 4; ++s) {
            int key = s * 16 + l16;
            const unsigned short* kr = Ks + key * 64;
            bf16x8 k0f = ld_bf8(kr + ((quad ^ sw) * 8));
            bf16x8 k1f = ld_bf8(kr + (((quad + 4) ^ sw) * 8));
            f32x4 z = {};
            z = __builtin_amdgcn_mfma_f32_16x16x32_bf16(k0f, qf[0], z, 0, 0, 0);
            st[s] = __builtin_amdgcn_mfma_f32_16x16x32_bf16(k1f, qf[1], z, 0, 0, 0);
        }

        // ---- mask + scale + online softmax (2 shuffles) ----
        float p[16];
        float tm = NEG_BIG;
        #pragma unroll
        for (int s = 0; s < 4; ++s)
            #pragma unroll
            for (int r = 0; r < 4; ++r) {
                int key = k0 + s * 16 + quad * 4 + r;
                float v = st[s][r] * 0.125f;
                v = (key <= q_abs) ? v : NEG_BIG;
                p[s * 4 + r] = v;
                tm = fmaxf(tm, v);
            }
        tm = fmaxf(tm, __shfl_xor(tm, 16, 64));
        tm = fmaxf(tm, __shfl_xor(tm, 32, 64));
        float mn    = fmaxf(m_s, tm);
        float alpha = __expf(m_s - mn);
        float ts = 0.f;
        #pragma unroll
        for (int i = 0; i < 16; ++i) { p[i] = __expf(p[i] - mn); ts += p[i]; }
        ts += __shfl_xor(ts, 16, 64);
        ts += __shfl_xor(ts, 32, 64);
        m_s = mn;
        l_s = l_s * alpha + ts;
        #pragma unroll
        for (int c = 0; c < 4; ++c)
            #pragma unroll
            for (int r = 0; r < 4; ++r) o[c][r] *= alpha;

        // ---- P^T -> wave-private LDS [q=l16][key], swizzled 16B chunks ----
        #pragma unroll
        for (int s = 0; s < 4; ++s)
            #pragma unroll
            for (int rp = 0; rp < 4; rp += 2) {
                int g = 2 * s + (quad >> 1);          // key chunk index
                uint32_t pk = (uint32_t)f2bf(p[s * 4 + rp]) |
                              ((uint32_t)f2bf(p[s * 4 + rp + 1]) << 16);
                *(uint32_t*)((char*)(pbuf + l16 * 64) + (g ^ sw) * 16 +
                             8 * (quad & 1) + 2 * rp) = pk;
            }
        bf16x8 pf0 = ld_bf8(pbuf + l16 * 64 + ((quad ^ sw) * 8));
        bf16x8 pf1 = ld_bf8(pbuf + l16 * 64 + (((quad + 4) ^ sw) * 8));

        // ---- O^T += V^T P^T : 4 channel-subtiles of 16 ----
        #pragma unroll
        for (int c = 0; c < 4; ++c) {
            const unsigned short* vr = Vs + (c * 16 + l16) * 64;
            bf16x8 v0f = ld_bf8(vr + ((quad ^ sw) * 8));
            bf16x8 v1f = ld_bf8(vr + (((quad + 4) ^ sw) * 8));
            o[c] = __builtin_amdgcn_mfma_f32_16x16x32_bf16(v0f, pf0, o[c], 0, 0, 0);
            o[c] = __builtin_amdgcn_mfma_f32_16x16x32_bf16(v1f, pf1, o[c], 0, 0, 0);
        }
        __syncthreads();
    }

    // epilogue: O^T C-layout row=ch=c*16+quad*4+r, col=q=l16
    float inv_l = 1.f / l_s;
    #pragma unroll
    for (int c = 0; c < 4; ++c) {
        union { unsigned short u[4]; uint2 q; } t;
        #pragma unroll
        for (int r = 0; r < 4; ++r) t.u[r] = f2bf(o[c][r] * inv_l);
        *(uint2*)(Y + (size_t)q_abs * C_DIM + h * HD + c * 16 + quad * 4) = t.q;
    }
}

extern "C" void kernel_launch(void* const* d_in, const int* in_sizes, int n_in,
                              void* d_out, int out_size, void* d_ws, size_t ws_size,
                              hipStream_t stream) {
    const float* x      = (const float*)d_in[0];   // [4096,1024] fp32
    const float* w_attn = (const float*)d_in[1];   // [3072,1024] fp32
    const float* w_proj = (const float*)d_in[2];   // [1024,1024] fp32
    float* out = (float*)d_out;                    // [4096,1024] fp32 (16 MB)

    // ws: [0,24MB) qkv bf16; [24,32MB) xb bf16 then y bf16 (xb dead after gemm1)
    unsigned short* qkv = (unsigned short*)d_ws;
    unsigned short* xb  = qkv + (size_t)T_SEQ * C3;
    unsigned short* y   = xb;
    unsigned short* wpb = qkv;                      // qkv dead after flash
    // d_out scratch (dead until gemm2): [0,8MB) Vt bf16 [1024][4096]; [8,14MB) wab
    unsigned short* Vt  = (unsigned short*)d_out;
    unsigned short* wab = Vt + (size_t)C_DIM * T_SEQ;

    cvt_f32_bf16<<<(T_SEQ * C_DIM / 8 + 255) / 256, 256, 0, stream>>>(x, xb, T_SEQ * C_DIM);
    cvt_f32_bf16<<<(C3 * C_DIM / 8 + 255) / 256, 256, 0, stream>>>(w_attn, wab, C3 * C_DIM);

    gemm_bt<unsigned short>
        <<<dim3(C3 / 128, T_SEQ / 128), 256, 0, stream>>>(xb, wab, qkv, Vt, T_SEQ, C3, C_DIM);

    flash_attn3<<<dim3(T_SEQ / 64, H_NUM), 256, 0, stream>>>(qkv, Vt, y);

    cvt_f32_bf16<<<(C_DIM * C_DIM / 8 + 255) / 256, 256, 0, stream>>>(w_proj, wpb, C_DIM * C_DIM);
    gemm_bt<float>
        <<<dim3(C_DIM / 128, T_SEQ / 128), 256, 0, stream>>>(y, wpb, out, nullptr, T_SEQ, C_DIM, C_DIM);
}

// Round 6
// 237.168 us; speedup vs baseline: 2.4681x; 1.2318x over previous
//
#include <hip/hip_runtime.h>
#include <hip/hip_bf16.h>
#include <stdint.h>

typedef __bf16 bf16x8 __attribute__((ext_vector_type(8)));
typedef float f32x4 __attribute__((ext_vector_type(4)));

#define T_SEQ 4096
#define C_DIM 1024
#define H_NUM 16
#define HD 64
#define C3 3072
#define NEG_BIG (-30000.0f)

__device__ __forceinline__ unsigned short f2bf(float f) {
    uint32_t u = __builtin_bit_cast(uint32_t, f);
    u += 0x7fffu + ((u >> 16) & 1u);
    return (unsigned short)(u >> 16);
}

__device__ __forceinline__ bf16x8 ld_bf8(const unsigned short* p) {
    return *reinterpret_cast<const bf16x8*>(p);
}

__device__ __forceinline__ void async_g2l16(const unsigned short* g, unsigned short* l) {
    __builtin_amdgcn_global_load_lds(
        (const __attribute__((address_space(1))) void*)g,
        (__attribute__((address_space(3))) void*)l, 16, 0, 0);
}

__device__ __forceinline__ void store_c(unsigned short* C, size_t idx, float v) { C[idx] = f2bf(v); }
__device__ __forceinline__ void store_c(float* C, size_t idx, float v)          { C[idx] = v; }

// fp32 -> bf16 elementwise convert, 8 elems/thread
__global__ void cvt_f32_bf16(const float* __restrict__ src, unsigned short* __restrict__ dst, int n) {
    int i = (blockIdx.x * blockDim.x + threadIdx.x) * 8;
    if (i >= n) return;
    float4 f0 = *(const float4*)(src + i);
    float4 f1 = *(const float4*)(src + i + 4);
    union { unsigned short u[8]; uint4 q; } t;
    t.u[0] = f2bf(f0.x); t.u[1] = f2bf(f0.y); t.u[2] = f2bf(f0.z); t.u[3] = f2bf(f0.w);
    t.u[4] = f2bf(f1.x); t.u[5] = f2bf(f1.y); t.u[6] = f2bf(f1.z); t.u[7] = f2bf(f1.w);
    *(uint4*)(dst + i) = t.q;
}

// V part of qkv [T][3C] -> Vt [C][T], 64x64 tiles through padded LDS.
__global__ __launch_bounds__(256) void v_transpose(
    const unsigned short* __restrict__ qkv, unsigned short* __restrict__ Vt)
{
    __shared__ unsigned short tile[64][72];
    const int t0 = blockIdx.x * 64, c0 = blockIdx.y * 64;
    const int r = threadIdx.x >> 2, q = threadIdx.x & 3;

    const unsigned short* src = qkv + (size_t)(t0 + r) * C3 + 2 * C_DIM + c0 + q * 16;
    *(uint4*)&tile[r][q * 16]     = *(const uint4*)src;
    *(uint4*)&tile[r][q * 16 + 8] = *(const uint4*)(src + 8);
    __syncthreads();

    union { unsigned short u[16]; uint4 v[2]; } o;
    #pragma unroll
    for (int j = 0; j < 16; ++j) o.u[j] = tile[q * 16 + j][r];
    unsigned short* dst = Vt + (size_t)(c0 + r) * T_SEQ + t0 + q * 16;
    *(uint4*)dst       = o.v[0];
    *(uint4*)(dst + 8) = o.v[1];
}

// C = A @ B^T, bf16, m97 async staging. 128x128 tile, BK=32.
template <typename TC>
__global__ __launch_bounds__(256, 2) void gemm_bt(
    const unsigned short* __restrict__ A, const unsigned short* __restrict__ B,
    TC* __restrict__ C, int M, int N, int K)
{
    __shared__ __attribute__((aligned(16))) unsigned short As[128 * 32];
    __shared__ __attribute__((aligned(16))) unsigned short Bs[128 * 32];

    const int tid  = threadIdx.x;
    const int wave = tid >> 6, lane = tid & 63;
    const int quad = lane >> 4, l16 = lane & 15;
    const int wm = wave >> 1, wn = wave & 1;
    const int m0 = blockIdx.y * 128, n0 = blockIdx.x * 128;

    const int srow = wave * 32 + (lane >> 2);
    const int scol = (lane & 3) * 8;

    f32x4 acc[4][4] = {};

    for (int k0 = 0; k0 < K; k0 += 32) {
        {
            const unsigned short* ga = A + (size_t)(m0 + srow) * K + k0 + scol;
            const unsigned short* gb = B + (size_t)(n0 + srow) * K + k0 + scol;
            unsigned short* la = As + (wave * 32) * 32;
            unsigned short* lb = Bs + (wave * 32) * 32;
            async_g2l16(ga, la);
            async_g2l16(ga + (size_t)16 * K, la + 16 * 32);
            async_g2l16(gb, lb);
            async_g2l16(gb + (size_t)16 * K, lb + 16 * 32);
        }
        __syncthreads();

        bf16x8 af[4], bf[4];
        #pragma unroll
        for (int i = 0; i < 4; ++i) {
            af[i] = ld_bf8(As + (wm * 64 + i * 16 + l16) * 32 + quad * 8);
            bf[i] = ld_bf8(Bs + (wn * 64 + i * 16 + l16) * 32 + quad * 8);
        }
        #pragma unroll
        for (int mt = 0; mt < 4; ++mt)
            #pragma unroll
            for (int nt = 0; nt < 4; ++nt)
                acc[mt][nt] = __builtin_amdgcn_mfma_f32_16x16x32_bf16(
                    af[mt], bf[nt], acc[mt][nt], 0, 0, 0);
        __syncthreads();
    }

    #pragma unroll
    for (int mt = 0; mt < 4; ++mt)
        #pragma unroll
        for (int nt = 0; nt < 4; ++nt)
            #pragma unroll
            for (int r = 0; r < 4; ++r) {
                int row = m0 + wm * 64 + mt * 16 + quad * 4 + r;
                int col = n0 + wn * 64 + nt * 16 + l16;
                store_c(C, (size_t)row * N + col, acc[mt][nt][r]);
            }
}

// One flash tile: S^T = K Q^T (log2-prescaled), online softmax, O^T += V^T P^T.
template <bool MASK>
__device__ __forceinline__ void fa_tile(
    const unsigned short* Ksb, const unsigned short* Vsb, unsigned short* pbuf,
    const bf16x8* qf, f32x4* o, float& m_s, float& l_s,
    int k0, int q_abs, int quad, int l16, int sw)
{
    f32x4 st[4];
    #pragma unroll
    for (int s = 0; s < 4; ++s) {
        const unsigned short* kr = Ksb + (s * 16 + l16) * 64;
        bf16x8 kf0 = ld_bf8(kr + ((quad ^ sw) * 8));
        bf16x8 kf1 = ld_bf8(kr + (((quad + 4) ^ sw) * 8));
        f32x4 z = {};
        z = __builtin_amdgcn_mfma_f32_16x16x32_bf16(kf0, qf[0], z, 0, 0, 0);
        st[s] = __builtin_amdgcn_mfma_f32_16x16x32_bf16(kf1, qf[1], z, 0, 0, 0);
    }

    float p[16];
    float tm = NEG_BIG;
    #pragma unroll
    for (int s = 0; s < 4; ++s)
        #pragma unroll
        for (int r = 0; r < 4; ++r) {
            float v = st[s][r];
            if (MASK) {
                int key = k0 + s * 16 + quad * 4 + r;
                v = (key <= q_abs) ? v : NEG_BIG;
            }
            p[s * 4 + r] = v;
            tm = fmaxf(tm, v);
        }
    tm = fmaxf(tm, __shfl_xor(tm, 16, 64));
    tm = fmaxf(tm, __shfl_xor(tm, 32, 64));
    float mn    = fmaxf(m_s, tm);
    float alpha = exp2f(m_s - mn);
    float ts = 0.f;
    #pragma unroll
    for (int i = 0; i < 16; ++i) { p[i] = exp2f(p[i] - mn); ts += p[i]; }
    ts += __shfl_xor(ts, 16, 64);
    ts += __shfl_xor(ts, 32, 64);
    m_s = mn;
    l_s = l_s * alpha + ts;
    #pragma unroll
    for (int c = 0; c < 4; ++c)
        #pragma unroll
        for (int r = 0; r < 4; ++r) o[c][r] *= alpha;

    // P^T -> wave-private swizzled LDS, then B-operand fragments
    #pragma unroll
    for (int s = 0; s < 4; ++s)
        #pragma unroll
        for (int rp = 0; rp < 4; rp += 2) {
            int g = 2 * s + (quad >> 1);
            uint32_t pk = (uint32_t)f2bf(p[s * 4 + rp]) |
                          ((uint32_t)f2bf(p[s * 4 + rp + 1]) << 16);
            *(uint32_t*)((char*)(pbuf + l16 * 64) + (g ^ sw) * 16 +
                         8 * (quad & 1) + 2 * rp) = pk;
        }
    bf16x8 pf0 = ld_bf8(pbuf + l16 * 64 + ((quad ^ sw) * 8));
    bf16x8 pf1 = ld_bf8(pbuf + l16 * 64 + (((quad + 4) ^ sw) * 8));

    #pragma unroll
    for (int c = 0; c < 4; ++c) {
        const unsigned short* vr = Vsb + (c * 16 + l16) * 64;
        o[c] = __builtin_amdgcn_mfma_f32_16x16x32_bf16(
            ld_bf8(vr + ((quad ^ sw) * 8)), pf0, o[c], 0, 0, 0);
        o[c] = __builtin_amdgcn_mfma_f32_16x16x32_bf16(
            ld_bf8(vr + (((quad + 4) ^ sw) * 8)), pf1, o[c], 0, 0, 0);
    }
}

// Flash v4: snake-balanced 1D grid, double-buffered K/V staging, 1 barrier/tile.
__global__ __launch_bounds__(256, 4) void flash_attn4(
    const unsigned short* __restrict__ qkv,
    const unsigned short* __restrict__ Vt,
    unsigned short* __restrict__ Y)
{
    __shared__ __attribute__((aligned(16))) unsigned short Ks[2][64 * 64];
    __shared__ __attribute__((aligned(16))) unsigned short Vs[2][64 * 64];
    __shared__ __attribute__((aligned(16))) unsigned short Pl[4][16 * 64];

    const int tid  = threadIdx.x;
    const int wave = tid >> 6, lane = tid & 63;
    const int quad = lane >> 4, l16 = lane & 15;

    // snake-balanced (head, qb): every group of 256 consecutive blocks covers
    // each slot once; the 4 rounds give each slot qb = {j, 63-j, 16+j, 47-j}
    // -> constant 130 tiles of work per dispatch slot.
    const int bi = blockIdx.x;
    const int rr = bi >> 8, ss = bi & 255;
    const int h  = ss & 15;
    const int j  = ss >> 4;
    const int qb = (rr == 0) ? j : (rr == 1) ? 63 - j : (rr == 2) ? 16 + j : 47 - j;

    const int q0w  = qb * 64 + wave * 16;
    const int q_abs = q0w + l16;
    const int sw = l16 & 7;

    // Q fragments, prescaled by 0.125*log2(e) (softmax in log2 domain)
    bf16x8 qf[2];
    {
        const float QS = 0.125f * 1.44269504f;
        const unsigned short* qp = qkv + (size_t)(q0w + l16) * C3 + h * HD + quad * 8;
        bf16x8 a = ld_bf8(qp), b = ld_bf8(qp + 32);
        #pragma unroll
        for (int i = 0; i < 8; ++i) {
            qf[0][i] = (__bf16)((float)a[i] * QS);
            qf[1][i] = (__bf16)((float)b[i] * QS);
        }
    }

    // staging map: 8 rows x 8 chunks per wave-call, XOR swizzle on global side
    const int srow = lane >> 3;
    const int schunk = (lane & 7) ^ srow;
    const unsigned short* kbase = qkv + C_DIM + (size_t)h * HD;
    const unsigned short* vbase = Vt + (size_t)h * HD * T_SEQ;
    auto stage = [&](int t, int b) {
        const int k0 = t * 64;
        #pragma unroll
        for (int jj = 0; jj < 2; ++jj) {
            int row0 = wave * 16 + jj * 8;
            int row  = row0 + srow;
            async_g2l16(kbase + (size_t)(k0 + row) * C3 + schunk * 8, Ks[b] + row0 * 64);
            async_g2l16(vbase + (size_t)row * T_SEQ + k0 + schunk * 8, Vs[b] + row0 * 64);
        }
    };

    f32x4 o[4] = {};
    float m_s = NEG_BIG, l_s = 0.f;
    unsigned short* pbuf = Pl[wave];

    const int ntiles = qb + 1;
    stage(0, 0);
    for (int t = 0; t < ntiles; ++t) {
        __syncthreads();   // drains this wave's stage(t) loads; all waves past tile t-1
        if (t + 1 < ntiles) {
            stage(t + 1, (t + 1) & 1);
            fa_tile<false>(Ks[t & 1], Vs[t & 1], pbuf, qf, o, m_s, l_s,
                           t * 64, q_abs, quad, l16, sw);
        } else {
            fa_tile<true>(Ks[t & 1], Vs[t & 1], pbuf, qf, o, m_s, l_s,
                          t * 64, q_abs, quad, l16, sw);
        }
    }

    float inv_l = 1.f / l_s;
    #pragma unroll
    for (int c = 0; c < 4; ++c) {
        union { unsigned short u[4]; uint2 q; } t;
        #pragma unroll
        for (int r = 0; r < 4; ++r) t.u[r] = f2bf(o[c][r] * inv_l);
        *(uint2*)(Y + (size_t)q_abs * C_DIM + h * HD + c * 16 + quad * 4) = t.q;
    }
}

extern "C" void kernel_launch(void* const* d_in, const int* in_sizes, int n_in,
                              void* d_out, int out_size, void* d_ws, size_t ws_size,
                              hipStream_t stream) {
    const float* x      = (const float*)d_in[0];   // [4096,1024] fp32
    const float* w_attn = (const float*)d_in[1];   // [3072,1024] fp32
    const float* w_proj = (const float*)d_in[2];   // [1024,1024] fp32
    float* out = (float*)d_out;                    // [4096,1024] fp32 (16 MB)

    // ws: [0,24MB) qkv bf16; [24,32MB) xb bf16 then y bf16 (xb dead after gemm1)
    unsigned short* qkv = (unsigned short*)d_ws;
    unsigned short* xb  = qkv + (size_t)T_SEQ * C3;
    unsigned short* y   = xb;
    unsigned short* wpb = qkv;                      // qkv dead after flash
    // d_out scratch (dead until gemm2): [0,8MB) Vt bf16 [1024][4096]; [8,14MB) wab
    unsigned short* Vt  = (unsigned short*)d_out;
    unsigned short* wab = Vt + (size_t)C_DIM * T_SEQ;

    cvt_f32_bf16<<<(T_SEQ * C_DIM / 8 + 255) / 256, 256, 0, stream>>>(x, xb, T_SEQ * C_DIM);
    cvt_f32_bf16<<<(C3 * C_DIM / 8 + 255) / 256, 256, 0, stream>>>(w_attn, wab, C3 * C_DIM);

    gemm_bt<unsigned short>
        <<<dim3(C3 / 128, T_SEQ / 128), 256, 0, stream>>>(xb, wab, qkv, T_SEQ, C3, C_DIM);

    v_transpose<<<dim3(T_SEQ / 64, C_DIM / 64), 256, 0, stream>>>(qkv, Vt);

    flash_attn4<<<dim3(T_SEQ / 64 * H_NUM), 256, 0, stream>>>(qkv, Vt, y);

    cvt_f32_bf16<<<(C_DIM * C_DIM / 8 + 255) / 256, 256, 0, stream>>>(w_proj, wpb, C_DIM * C_DIM);
    gemm_bt<float>
        <<<dim3(C_DIM / 128, T_SEQ / 128), 256, 0, stream>>>(y, wpb, out, T_SEQ, C_DIM, C_DIM);
}

// Round 8
// 223.951 us; speedup vs baseline: 2.6138x; 1.0590x over previous
//
#include <hip/hip_runtime.h>
#include <hip/hip_bf16.h>
#include <stdint.h>

typedef __bf16 bf16x8 __attribute__((ext_vector_type(8)));
typedef float f32x4 __attribute__((ext_vector_type(4)));

#define T_SEQ 4096
#define C_DIM 1024
#define H_NUM 16
#define HD 64
#define C3 3072
#define NEG_BIG (-30000.0f)

__device__ __forceinline__ unsigned short f2bf(float f) {
    uint32_t u = __builtin_bit_cast(uint32_t, f);
    u += 0x7fffu + ((u >> 16) & 1u);
    return (unsigned short)(u >> 16);
}

__device__ __forceinline__ uint32_t pk_bf16(float a, float b) {
    __hip_bfloat162 h = __float22bfloat162_rn(float2{a, b});
    uint32_t u;
    __builtin_memcpy(&u, &h, sizeof(u));
    return u;
}

__device__ __forceinline__ bf16x8 ld_bf8(const unsigned short* p) {
    return *reinterpret_cast<const bf16x8*>(p);
}

__device__ __forceinline__ void async_g2l16(const unsigned short* g, unsigned short* l) {
    __builtin_amdgcn_global_load_lds(
        (const __attribute__((address_space(1))) void*)g,
        (__attribute__((address_space(3))) void*)l, 16, 0, 0);
}

__device__ __forceinline__ void store_c(unsigned short* C, size_t idx, float v) { C[idx] = f2bf(v); }
__device__ __forceinline__ void store_c(float* C, size_t idx, float v)          { C[idx] = v; }

// fp32 -> bf16 elementwise convert, 8 elems/thread
__global__ void cvt_f32_bf16(const float* __restrict__ src, unsigned short* __restrict__ dst, int n) {
    int i = (blockIdx.x * blockDim.x + threadIdx.x) * 8;
    if (i >= n) return;
    float4 f0 = *(const float4*)(src + i);
    float4 f1 = *(const float4*)(src + i + 4);
    union { uint32_t w[4]; uint4 q; } t;
    t.w[0] = pk_bf16(f0.x, f0.y);
    t.w[1] = pk_bf16(f0.z, f0.w);
    t.w[2] = pk_bf16(f1.x, f1.y);
    t.w[3] = pk_bf16(f1.z, f1.w);
    *(uint4*)(dst + i) = t.q;
}

// V part of qkv [T][3C] -> Vt [C][T], 64x64 tiles through padded LDS.
__global__ __launch_bounds__(256) void v_transpose(
    const unsigned short* __restrict__ qkv, unsigned short* __restrict__ Vt)
{
    __shared__ unsigned short tile[64][72];
    const int t0 = blockIdx.x * 64, c0 = blockIdx.y * 64;
    const int r = threadIdx.x >> 2, q = threadIdx.x & 3;

    const unsigned short* src = qkv + (size_t)(t0 + r) * C3 + 2 * C_DIM + c0 + q * 16;
    *(uint4*)&tile[r][q * 16]     = *(const uint4*)src;
    *(uint4*)&tile[r][q * 16 + 8] = *(const uint4*)(src + 8);
    __syncthreads();

    union { unsigned short u[16]; uint4 v[2]; } o;
    #pragma unroll
    for (int j = 0; j < 16; ++j) o.u[j] = tile[q * 16 + j][r];
    unsigned short* dst = Vt + (size_t)(c0 + r) * T_SEQ + t0 + q * 16;
    *(uint4*)dst       = o.v[0];
    *(uint4*)(dst + 8) = o.v[1];
}

// C = A @ B^T, bf16, m97 async staging. 128x128 tile, BK=32.
template <typename TC>
__global__ __launch_bounds__(256, 2) void gemm_bt(
    const unsigned short* __restrict__ A, const unsigned short* __restrict__ B,
    TC* __restrict__ C, int M, int N, int K)
{
    __shared__ __attribute__((aligned(16))) unsigned short As[128 * 32];
    __shared__ __attribute__((aligned(16))) unsigned short Bs[128 * 32];

    const int tid  = threadIdx.x;
    const int wave = tid >> 6, lane = tid & 63;
    const int quad = lane >> 4, l16 = lane & 15;
    const int wm = wave >> 1, wn = wave & 1;
    const int m0 = blockIdx.y * 128, n0 = blockIdx.x * 128;

    const int srow = wave * 32 + (lane >> 2);
    const int scol = (lane & 3) * 8;

    f32x4 acc[4][4] = {};

    for (int k0 = 0; k0 < K; k0 += 32) {
        {
            const unsigned short* ga = A + (size_t)(m0 + srow) * K + k0 + scol;
            const unsigned short* gb = B + (size_t)(n0 + srow) * K + k0 + scol;
            unsigned short* la = As + (wave * 32) * 32;
            unsigned short* lb = Bs + (wave * 32) * 32;
            async_g2l16(ga, la);
            async_g2l16(ga + (size_t)16 * K, la + 16 * 32);
            async_g2l16(gb, lb);
            async_g2l16(gb + (size_t)16 * K, lb + 16 * 32);
        }
        __syncthreads();

        bf16x8 af[4], bf[4];
        #pragma unroll
        for (int i = 0; i < 4; ++i) {
            af[i] = ld_bf8(As + (wm * 64 + i * 16 + l16) * 32 + quad * 8);
            bf[i] = ld_bf8(Bs + (wn * 64 + i * 16 + l16) * 32 + quad * 8);
        }
        #pragma unroll
        for (int mt = 0; mt < 4; ++mt)
            #pragma unroll
            for (int nt = 0; nt < 4; ++nt)
                acc[mt][nt] = __builtin_amdgcn_mfma_f32_16x16x32_bf16(
                    af[mt], bf[nt], acc[mt][nt], 0, 0, 0);
        __syncthreads();
    }

    #pragma unroll
    for (int mt = 0; mt < 4; ++mt)
        #pragma unroll
        for (int nt = 0; nt < 4; ++nt)
            #pragma unroll
            for (int r = 0; r < 4; ++r) {
                int row = m0 + wm * 64 + mt * 16 + quad * 4 + r;
                int col = n0 + wn * 64 + nt * 16 + l16;
                store_c(C, (size_t)row * N + col, acc[mt][nt][r]);
            }
}

// One flash tile. fo0/fo1 = precomputed swizzled fragment element offsets.
template <bool MASK>
__device__ __forceinline__ void fa_tile(
    const unsigned short* Ksb, const unsigned short* Vsb, unsigned short* pbuf,
    const bf16x8* qf, f32x4* o, float& m_s, float& l_s,
    int k0, int q_abs, int quad, int l16, int sw, int fo0, int fo1)
{
    const unsigned short* krow = Ksb + l16 * 64;
    f32x4 st[4];
    #pragma unroll
    for (int s = 0; s < 4; ++s) {
        bf16x8 kf0 = ld_bf8(krow + s * 1024 + fo0);
        bf16x8 kf1 = ld_bf8(krow + s * 1024 + fo1);
        f32x4 z = {};
        z = __builtin_amdgcn_mfma_f32_16x16x32_bf16(kf0, qf[0], z, 0, 0, 0);
        st[s] = __builtin_amdgcn_mfma_f32_16x16x32_bf16(kf1, qf[1], z, 0, 0, 0);
    }

    float tm = NEG_BIG;
    #pragma unroll
    for (int s = 0; s < 4; ++s)
        #pragma unroll
        for (int r = 0; r < 4; ++r) {
            float v = st[s][r];
            if (MASK) {
                int key = k0 + s * 16 + quad * 4 + r;
                v = (key <= q_abs) ? v : NEG_BIG;
                st[s][r] = v;
            }
            tm = fmaxf(tm, v);
        }
    tm = fmaxf(tm, __shfl_xor(tm, 16, 64));
    tm = fmaxf(tm, __shfl_xor(tm, 32, 64));
    float mn    = fmaxf(m_s, tm);
    float alpha = __builtin_amdgcn_exp2f(m_s - mn);
    float ts = 0.f;
    #pragma unroll
    for (int s = 0; s < 4; ++s)
        #pragma unroll
        for (int r = 0; r < 4; ++r) {
            float e = __builtin_amdgcn_exp2f(st[s][r] - mn);
            st[s][r] = e;
            ts += e;
        }
    ts += __shfl_xor(ts, 16, 64);
    ts += __shfl_xor(ts, 32, 64);
    m_s = mn;
    l_s = l_s * alpha + ts;
    #pragma unroll
    for (int c = 0; c < 4; ++c)
        #pragma unroll
        for (int r = 0; r < 4; ++r) o[c][r] *= alpha;

    // P^T -> wave-private swizzled LDS (packed bf16 stores)
    #pragma unroll
    for (int s = 0; s < 4; ++s)
        #pragma unroll
        for (int rp = 0; rp < 4; rp += 2) {
            int g = 2 * s + (quad >> 1);
            uint32_t pk = pk_bf16(st[s][rp], st[s][rp + 1]);
            *(uint32_t*)((char*)(pbuf + l16 * 64) + (g ^ sw) * 16 +
                         8 * (quad & 1) + 2 * rp) = pk;
        }
    bf16x8 pf0 = ld_bf8(pbuf + l16 * 64 + fo0);
    bf16x8 pf1 = ld_bf8(pbuf + l16 * 64 + fo1);

    const unsigned short* vrow = Vsb + l16 * 64;
    #pragma unroll
    for (int c = 0; c < 4; ++c) {
        o[c] = __builtin_amdgcn_mfma_f32_16x16x32_bf16(
            ld_bf8(vrow + c * 1024 + fo0), pf0, o[c], 0, 0, 0);
        o[c] = __builtin_amdgcn_mfma_f32_16x16x32_bf16(
            ld_bf8(vrow + c * 1024 + fo1), pf1, o[c], 0, 0, 0);
    }
}

// Flash v5: snake-balanced grid, double-buffered staging, raw exp2, pk cvt,
// pointer-increment staging addresses.
__global__ __launch_bounds__(256, 4) void flash_attn5(
    const unsigned short* __restrict__ qkv,
    const unsigned short* __restrict__ Vt,
    unsigned short* __restrict__ Y)
{
    __shared__ __attribute__((aligned(16))) unsigned short Ks[2][64 * 64];
    __shared__ __attribute__((aligned(16))) unsigned short Vs[2][64 * 64];
    __shared__ __attribute__((aligned(16))) unsigned short Pl[4][16 * 64];

    const int tid  = threadIdx.x;
    const int wave = tid >> 6, lane = tid & 63;
    const int quad = lane >> 4, l16 = lane & 15;

    const int bi = blockIdx.x;
    const int rr = bi >> 8, ss = bi & 255;
    const int h  = ss & 15;
    const int j  = ss >> 4;
    const int qb = (rr == 0) ? j : (rr == 1) ? 63 - j : (rr == 2) ? 16 + j : 47 - j;

    const int q0w   = qb * 64 + wave * 16;
    const int q_abs = q0w + l16;
    const int sw  = l16 & 7;
    const int fo0 = (quad ^ sw) * 8;
    const int fo1 = ((quad + 4) ^ sw) * 8;

    bf16x8 qf[2];
    {
        const float QS = 0.125f * 1.44269504f;
        const unsigned short* qp = qkv + (size_t)(q0w + l16) * C3 + h * HD + quad * 8;
        bf16x8 a = ld_bf8(qp), b = ld_bf8(qp + 32);
        #pragma unroll
        for (int i = 0; i < 8; ++i) {
            qf[0][i] = (__bf16)((float)a[i] * QS);
            qf[1][i] = (__bf16)((float)b[i] * QS);
        }
    }

    const int srow = lane >> 3;
    const int schunk = (lane & 7) ^ srow;
    const unsigned short* kp0 =
        qkv + (size_t)(wave * 16 + srow) * C3 + C_DIM + h * HD + schunk * 8;
    const unsigned short* kp1 = kp0 + (size_t)8 * C3;
    const unsigned short* vp0 =
        Vt + (size_t)(h * HD + wave * 16 + srow) * T_SEQ + schunk * 8;
    const unsigned short* vp1 = vp0 + (size_t)8 * T_SEQ;
    unsigned short* lk0  = Ks[0] + (wave * 16) * 64;
    unsigned short* lk0b = lk0 + 8 * 64;
    unsigned short* lv0  = Vs[0] + (wave * 16) * 64;
    unsigned short* lv0b = lv0 + 8 * 64;
    const int lds_db = 64 * 64;

    f32x4 o[4] = {};
    float m_s = NEG_BIG, l_s = 0.f;
    unsigned short* pbuf = Pl[wave];

    const int ntiles = qb + 1;
    async_g2l16(kp0, lk0);  async_g2l16(kp1, lk0b);
    async_g2l16(vp0, lv0);  async_g2l16(vp1, lv0b);
    kp0 += (size_t)64 * C3; kp1 += (size_t)64 * C3;
    vp0 += 64;              vp1 += 64;

    for (int t = 0; t < ntiles; ++t) {
        __syncthreads();
        const int b = t & 1;
        if (t + 1 < ntiles) {
            const int nb = 1 - b;
            async_g2l16(kp0, lk0 + nb * lds_db);
            async_g2l16(kp1, lk0b + nb * lds_db);
            async_g2l16(vp0, lv0 + nb * lds_db);
            async_g2l16(vp1, lv0b + nb * lds_db);
            kp0 += (size_t)64 * C3; kp1 += (size_t)64 * C3;
            vp0 += 64;              vp1 += 64;
            fa_tile<false>(Ks[b], Vs[b], pbuf, qf, o, m_s, l_s,
                           t * 64, q_abs, quad, l16, sw, fo0, fo1);
        } else {
            fa_tile<true>(Ks[b], Vs[b], pbuf, qf, o, m_s, l_s,
                          t * 64, q_abs, quad, l16, sw, fo0, fo1);
        }
    }

    float inv_l = 1.f / l_s;
    #pragma unroll
    for (int c = 0; c < 4; ++c) {
        union { uint32_t w[2]; uint2 q; } t;
        t.w[0] = pk_bf16(o[c][0] * inv_l, o[c][1] * inv_l);
        t.w[1] = pk_bf16(o[c][2] * inv_l, o[c][3] * inv_l);
        *(uint2*)(Y + (size_t)q_abs * C_DIM + h * HD + c * 16 + quad * 4) = t.q;
    }
}

extern "C" void kernel_launch(void* const* d_in, const int* in_sizes, int n_in,
                              void* d_out, int out_size, void* d_ws, size_t ws_size,
                              hipStream_t stream) {
    const float* x      = (const float*)d_in[0];
    const float* w_attn = (const float*)d_in[1];
    const float* w_proj = (const float*)d_in[2];
    float* out = (float*)d_out;

    unsigned short* qkv = (unsigned short*)d_ws;
    unsigned short* xb  = qkv + (size_t)T_SEQ * C3;
    unsigned short* y   = xb;
    unsigned short* wpb = qkv;
    unsigned short* Vt  = (unsigned short*)d_out;
    unsigned short* wab = Vt + (size_t)C_DIM * T_SEQ;

    cvt_f32_bf16<<<(T_SEQ * C_DIM / 8 + 255) / 256, 256, 0, stream>>>(x, xb, T_SEQ * C_DIM);
    cvt_f32_bf16<<<(C3 * C_DIM / 8 + 255) / 256, 256, 0, stream>>>(w_attn, wab, C3 * C_DIM);

    gemm_bt<unsigned short>
        <<<dim3(C3 / 128, T_SEQ / 128), 256, 0, stream>>>(xb, wab, qkv, T_SEQ, C3, C_DIM);

    v_transpose<<<dim3(T_SEQ / 64, C_DIM / 64), 256, 0, stream>>>(qkv, Vt);

    flash_attn5<<<dim3(T_SEQ / 64 * H_NUM), 256, 0, stream>>>(qkv, Vt, y);

    cvt_f32_bf16<<<(C_DIM * C_DIM / 8 + 255) / 256, 256, 0, stream>>>(w_proj, wpb, C_DIM * C_DIM);
    gemm_bt<float>
        <<<dim3(C_DIM / 128, T_SEQ / 128), 256, 0, stream>>>(y, wpb, out, T_SEQ, C_DIM, C_DIM);
}

// Round 9
// 220.549 us; speedup vs baseline: 2.6541x; 1.0154x over previous
//
#include <hip/hip_runtime.h>
#include <hip/hip_bf16.h>
#include <stdint.h>

typedef __bf16 bf16x8 __attribute__((ext_vector_type(8)));
typedef float f32x4 __attribute__((ext_vector_type(4)));

#define T_SEQ 4096
#define C_DIM 1024
#define H_NUM 16
#define HD 64
#define C3 3072
#define NEG_BIG (-30000.0f)

__device__ __forceinline__ unsigned short f2bf(float f) {
    uint32_t u = __builtin_bit_cast(uint32_t, f);
    u += 0x7fffu + ((u >> 16) & 1u);
    return (unsigned short)(u >> 16);
}

__device__ __forceinline__ uint32_t pk_bf16(float a, float b) {
    __hip_bfloat162 h = __float22bfloat162_rn(float2{a, b});
    uint32_t u;
    __builtin_memcpy(&u, &h, sizeof(u));
    return u;
}

__device__ __forceinline__ bf16x8 ld_bf8(const unsigned short* p) {
    return *reinterpret_cast<const bf16x8*>(p);
}

__device__ __forceinline__ void async_g2l16(const unsigned short* g, unsigned short* l) {
    __builtin_amdgcn_global_load_lds(
        (const __attribute__((address_space(1))) void*)g,
        (__attribute__((address_space(3))) void*)l, 16, 0, 0);
}

__device__ __forceinline__ void store_c(unsigned short* C, size_t idx, float v) { C[idx] = f2bf(v); }
__device__ __forceinline__ void store_c(float* C, size_t idx, float v)          { C[idx] = v; }

__device__ __forceinline__ void cvt8(const float* src, unsigned short* dst) {
    float4 f0 = *(const float4*)src;
    float4 f1 = *(const float4*)(src + 4);
    union { uint32_t w[4]; uint4 q; } t;
    t.w[0] = pk_bf16(f0.x, f0.y);
    t.w[1] = pk_bf16(f0.z, f0.w);
    t.w[2] = pk_bf16(f1.x, f1.y);
    t.w[3] = pk_bf16(f1.z, f1.w);
    *(uint4*)dst = t.q;
}

// x and w_attn fp32 -> bf16 in one launch (concatenated index space)
__global__ void cvt_xw(const float* __restrict__ x, const float* __restrict__ wa,
                       unsigned short* __restrict__ xb, unsigned short* __restrict__ wab) {
    int i = (blockIdx.x * blockDim.x + threadIdx.x) * 8;
    if (i < T_SEQ * C_DIM) cvt8(x + i, xb + i);
    else {
        int k = i - T_SEQ * C_DIM;
        if (k < C3 * C_DIM) cvt8(wa + k, wab + k);
    }
}

__global__ void cvt_f32_bf16(const float* __restrict__ src, unsigned short* __restrict__ dst, int n) {
    int i = (blockIdx.x * blockDim.x + threadIdx.x) * 8;
    if (i >= n) return;
    cvt8(src + i, dst + i);
}

// V part of qkv [T][3C] -> Vt [C][T], 64x64 tiles through padded LDS.
__global__ __launch_bounds__(256) void v_transpose(
    const unsigned short* __restrict__ qkv, unsigned short* __restrict__ Vt)
{
    __shared__ unsigned short tile[64][72];
    const int t0 = blockIdx.x * 64, c0 = blockIdx.y * 64;
    const int r = threadIdx.x >> 2, q = threadIdx.x & 3;

    const unsigned short* src = qkv + (size_t)(t0 + r) * C3 + 2 * C_DIM + c0 + q * 16;
    *(uint4*)&tile[r][q * 16]     = *(const uint4*)src;
    *(uint4*)&tile[r][q * 16 + 8] = *(const uint4*)(src + 8);
    __syncthreads();

    union { unsigned short u[16]; uint4 v[2]; } o;
    #pragma unroll
    for (int j = 0; j < 16; ++j) o.u[j] = tile[q * 16 + j][r];
    unsigned short* dst = Vt + (size_t)(c0 + r) * T_SEQ + t0 + q * 16;
    *(uint4*)dst       = o.v[0];
    *(uint4*)(dst + 8) = o.v[1];
}

// C = A @ B^T, bf16, m97 async staging. 128x128 tile, BK=32.
template <typename TC>
__global__ __launch_bounds__(256, 2) void gemm_bt(
    const unsigned short* __restrict__ A, const unsigned short* __restrict__ B,
    TC* __restrict__ C, int M, int N, int K)
{
    __shared__ __attribute__((aligned(16))) unsigned short As[128 * 32];
    __shared__ __attribute__((aligned(16))) unsigned short Bs[128 * 32];

    const int tid  = threadIdx.x;
    const int wave = tid >> 6, lane = tid & 63;
    const int quad = lane >> 4, l16 = lane & 15;
    const int wm = wave >> 1, wn = wave & 1;
    const int m0 = blockIdx.y * 128, n0 = blockIdx.x * 128;

    const int srow = wave * 32 + (lane >> 2);
    const int scol = (lane & 3) * 8;

    f32x4 acc[4][4] = {};

    for (int k0 = 0; k0 < K; k0 += 32) {
        {
            const unsigned short* ga = A + (size_t)(m0 + srow) * K + k0 + scol;
            const unsigned short* gb = B + (size_t)(n0 + srow) * K + k0 + scol;
            unsigned short* la = As + (wave * 32) * 32;
            unsigned short* lb = Bs + (wave * 32) * 32;
            async_g2l16(ga, la);
            async_g2l16(ga + (size_t)16 * K, la + 16 * 32);
            async_g2l16(gb, lb);
            async_g2l16(gb + (size_t)16 * K, lb + 16 * 32);
        }
        __syncthreads();

        bf16x8 af[4], bf[4];
        #pragma unroll
        for (int i = 0; i < 4; ++i) {
            af[i] = ld_bf8(As + (wm * 64 + i * 16 + l16) * 32 + quad * 8);
            bf[i] = ld_bf8(Bs + (wn * 64 + i * 16 + l16) * 32 + quad * 8);
        }
        #pragma unroll
        for (int mt = 0; mt < 4; ++mt)
            #pragma unroll
            for (int nt = 0; nt < 4; ++nt)
                acc[mt][nt] = __builtin_amdgcn_mfma_f32_16x16x32_bf16(
                    af[mt], bf[nt], acc[mt][nt], 0, 0, 0);
        __syncthreads();
    }

    #pragma unroll
    for (int mt = 0; mt < 4; ++mt)
        #pragma unroll
        for (int nt = 0; nt < 4; ++nt)
            #pragma unroll
            for (int r = 0; r < 4; ++r) {
                int row = m0 + wm * 64 + mt * 16 + quad * 4 + r;
                int col = n0 + wn * 64 + nt * 16 + l16;
                store_c(C, (size_t)row * N + col, acc[mt][nt][r]);
            }
}

#define PL_STRIDE 2848   // 32*64 P rows + pad: pins LDS total >53.3KB -> 2 blocks/CU

// One flash tile, 32 q-rows/wave (2 q-subtiles), max-free softmax.
template <bool MASK>
__device__ __forceinline__ void fa6_tile(
    const unsigned short* Ksb, const unsigned short* Vsb, unsigned short* pbuf,
    const bf16x8 qf[2][2], f32x4 o[2][4], float* l_part,
    int k0, int q_abs0, int quad, int l16, int sw, int fo0, int fo1)
{
    // K fragments once, shared by both q-subtiles
    const unsigned short* krow = Ksb + l16 * 64;
    bf16x8 kf[4][2];
    #pragma unroll
    for (int s = 0; s < 4; ++s) {
        kf[s][0] = ld_bf8(krow + s * 1024 + fo0);
        kf[s][1] = ld_bf8(krow + s * 1024 + fo1);
    }

    #pragma unroll
    for (int qs = 0; qs < 2; ++qs) {
        f32x4 st[4];
        #pragma unroll
        for (int s = 0; s < 4; ++s) {
            f32x4 z = {};
            z = __builtin_amdgcn_mfma_f32_16x16x32_bf16(kf[s][0], qf[qs][0], z, 0, 0, 0);
            st[s] = __builtin_amdgcn_mfma_f32_16x16x32_bf16(kf[s][1], qf[qs][1], z, 0, 0, 0);
        }
        float ts = 0.f;
        #pragma unroll
        for (int s = 0; s < 4; ++s)
            #pragma unroll
            for (int r = 0; r < 4; ++r) {
                float v = st[s][r];
                if (MASK) {
                    int key = k0 + s * 16 + quad * 4 + r;
                    v = (key <= q_abs0 + qs * 16) ? v : NEG_BIG;
                }
                float e = __builtin_amdgcn_exp2f(v);   // exp2(-30000) = 0
                st[s][r] = e;
                ts += e;
            }
        l_part[qs] += ts;

        // P^T -> wave-private swizzled LDS, b64 stores (keys quad*4..+4 x2 contiguous)
        unsigned short* prow = pbuf + (qs * 16 + l16) * 64;
        #pragma unroll
        for (int s = 0; s < 4; ++s) {
            int g = 2 * s + (quad >> 1);
            uint2 pk;
            pk.x = pk_bf16(st[s][0], st[s][1]);
            pk.y = pk_bf16(st[s][2], st[s][3]);
            *(uint2*)((char*)prow + (g ^ sw) * 16 + 8 * (quad & 1)) = pk;
        }
    }

    // V fragments once, shared by both q-subtiles
    const unsigned short* vrow = Vsb + l16 * 64;
    bf16x8 vf[4][2];
    #pragma unroll
    for (int c = 0; c < 4; ++c) {
        vf[c][0] = ld_bf8(vrow + c * 1024 + fo0);
        vf[c][1] = ld_bf8(vrow + c * 1024 + fo1);
    }
    #pragma unroll
    for (int qs = 0; qs < 2; ++qs) {
        const unsigned short* prow = pbuf + (qs * 16 + l16) * 64;
        bf16x8 pf0 = ld_bf8(prow + fo0);
        bf16x8 pf1 = ld_bf8(prow + fo1);
        #pragma unroll
        for (int c = 0; c < 4; ++c) {
            o[qs][c] = __builtin_amdgcn_mfma_f32_16x16x32_bf16(vf[c][0], pf0, o[qs][c], 0, 0, 0);
            o[qs][c] = __builtin_amdgcn_mfma_f32_16x16x32_bf16(vf[c][1], pf1, o[qs][c], 0, 0, 0);
        }
    }
}

// Flash v6: 128 q-rows/block (32/wave), 512 equal-length blocks, max-free
// softmax, double-buffered K/V staging.
__global__ __launch_bounds__(256, 2) void flash_attn6(
    const unsigned short* __restrict__ qkv,
    const unsigned short* __restrict__ Vt,
    unsigned short* __restrict__ Y)
{
    __shared__ __attribute__((aligned(16))) unsigned short Ks[2][64 * 64];
    __shared__ __attribute__((aligned(16))) unsigned short Vs[2][64 * 64];
    __shared__ __attribute__((aligned(16))) unsigned short Pl[4][PL_STRIDE];

    const int tid  = threadIdx.x;
    const int wave = tid >> 6, lane = tid & 63;
    const int quad = lane >> 4, l16 = lane & 15;

    // 512 blocks: slot (h, j) x 2 rounds; qb = {j, 31-j} -> 68 tiles/block, equal.
    const int bi = blockIdx.x;
    const int rr = bi >> 8, ss = bi & 255;
    const int h  = ss & 15;
    const int j  = ss >> 4;
    const int qb = rr ? (31 - j) : j;          // [0,32), 128 q-rows each

    const int q0w    = qb * 128 + wave * 32;
    const int q_abs0 = q0w + l16;              // qs=0 row; qs=1 adds 16
    const int sw  = l16 & 7;
    const int fo0 = (quad ^ sw) * 8;
    const int fo1 = ((quad + 4) ^ sw) * 8;

    // Q fragments (B-operand), prescaled by 0.125*log2(e); 2 q-subtiles
    bf16x8 qf[2][2];
    {
        const float QS = 0.125f * 1.44269504f;
        #pragma unroll
        for (int qs = 0; qs < 2; ++qs) {
            const unsigned short* qp =
                qkv + (size_t)(q0w + qs * 16 + l16) * C3 + h * HD + quad * 8;
            bf16x8 a = ld_bf8(qp), b = ld_bf8(qp + 32);
            #pragma unroll
            for (int i = 0; i < 8; ++i) {
                qf[qs][0][i] = (__bf16)((float)a[i] * QS);
                qf[qs][1][i] = (__bf16)((float)b[i] * QS);
            }
        }
    }

    // staging: 8 rows x 8 swizzled 16B chunks per wave-call, pointer-increment
    const int srow = lane >> 3;
    const int schunk = (lane & 7) ^ srow;
    const unsigned short* kp0 =
        qkv + (size_t)(wave * 16 + srow) * C3 + C_DIM + h * HD + schunk * 8;
    const unsigned short* kp1 = kp0 + (size_t)8 * C3;
    const unsigned short* vp0 =
        Vt + (size_t)(h * HD + wave * 16 + srow) * T_SEQ + schunk * 8;
    const unsigned short* vp1 = vp0 + (size_t)8 * T_SEQ;
    unsigned short* lk0  = Ks[0] + (wave * 16) * 64;
    unsigned short* lk0b = lk0 + 8 * 64;
    unsigned short* lv0  = Vs[0] + (wave * 16) * 64;
    unsigned short* lv0b = lv0 + 8 * 64;
    const int lds_db = 64 * 64;

    f32x4 o[2][4] = {};
    float l_part[2] = {0.f, 0.f};
    unsigned short* pbuf = Pl[wave];

    const int ntiles = 2 * qb + 2;
    const int mask_t = 2 * qb + (wave >> 1);   // waves 0,1 end at 2qb; 2,3 at 2qb+1

    async_g2l16(kp0, lk0);  async_g2l16(kp1, lk0b);
    async_g2l16(vp0, lv0);  async_g2l16(vp1, lv0b);
    kp0 += (size_t)64 * C3; kp1 += (size_t)64 * C3;
    vp0 += 64;              vp1 += 64;

    for (int t = 0; t < ntiles; ++t) {
        __syncthreads();
        const int b = t & 1;
        if (t + 1 < ntiles) {
            const int nb = 1 - b;
            async_g2l16(kp0, lk0 + nb * lds_db);
            async_g2l16(kp1, lk0b + nb * lds_db);
            async_g2l16(vp0, lv0 + nb * lds_db);
            async_g2l16(vp1, lv0b + nb * lds_db);
            kp0 += (size_t)64 * C3; kp1 += (size_t)64 * C3;
            vp0 += 64;              vp1 += 64;
        }
        if (t < mask_t) {
            fa6_tile<false>(Ks[b], Vs[b], pbuf, qf, o, l_part,
                            t * 64, q_abs0, quad, l16, sw, fo0, fo1);
        } else if (t == mask_t) {
            fa6_tile<true>(Ks[b], Vs[b], pbuf, qf, o, l_part,
                           t * 64, q_abs0, quad, l16, sw, fo0, fo1);
        }
        // waves 0,1 idle (barrier only) on tile 2qb+1
    }

    // l: lanes of the 4 quads hold disjoint key-subsets per q row -> 2 shuffles
    #pragma unroll
    for (int qs = 0; qs < 2; ++qs) {
        float l = l_part[qs];
        l += __shfl_xor(l, 16, 64);
        l += __shfl_xor(l, 32, 64);
        float inv_l = 1.f / l;
        #pragma unroll
        for (int c = 0; c < 4; ++c) {
            union { uint32_t w[2]; uint2 q; } t;
            t.w[0] = pk_bf16(o[qs][c][0] * inv_l, o[qs][c][1] * inv_l);
            t.w[1] = pk_bf16(o[qs][c][2] * inv_l, o[qs][c][3] * inv_l);
            *(uint2*)(Y + (size_t)(q_abs0 + qs * 16) * C_DIM + h * HD + c * 16 + quad * 4) = t.q;
        }
    }
}

extern "C" void kernel_launch(void* const* d_in, const int* in_sizes, int n_in,
                              void* d_out, int out_size, void* d_ws, size_t ws_size,
                              hipStream_t stream) {
    const float* x      = (const float*)d_in[0];
    const float* w_attn = (const float*)d_in[1];
    const float* w_proj = (const float*)d_in[2];
    float* out = (float*)d_out;

    unsigned short* qkv = (unsigned short*)d_ws;            // [4096,3072] bf16
    unsigned short* xb  = qkv + (size_t)T_SEQ * C3;         // [4096,1024] bf16
    unsigned short* y   = xb;                               // alias after gemm1
    unsigned short* wpb = qkv;                              // alias after flash
    unsigned short* Vt  = (unsigned short*)d_out;           // [1024][4096] bf16
    unsigned short* wab = Vt + (size_t)C_DIM * T_SEQ;       // [3072,1024] bf16

    cvt_xw<<<(T_SEQ * C_DIM + C3 * C_DIM) / 8 / 256, 256, 0, stream>>>(x, w_attn, xb, wab);

    gemm_bt<unsigned short>
        <<<dim3(C3 / 128, T_SEQ / 128), 256, 0, stream>>>(xb, wab, qkv, T_SEQ, C3, C_DIM);

    v_transpose<<<dim3(T_SEQ / 64, C_DIM / 64), 256, 0, stream>>>(qkv, Vt);

    flash_attn6<<<dim3(512), 256, 0, stream>>>(qkv, Vt, y);

    cvt_f32_bf16<<<(C_DIM * C_DIM / 8 + 255) / 256, 256, 0, stream>>>(w_proj, wpb, C_DIM * C_DIM);
    gemm_bt<float>
        <<<dim3(C_DIM / 128, T_SEQ / 128), 256, 0, stream>>>(y, wpb, out, T_SEQ, C_DIM, C_DIM);
}

// Round 10
// 218.738 us; speedup vs baseline: 2.6761x; 1.0083x over previous
//
#include <hip/hip_runtime.h>
#include <hip/hip_bf16.h>
#include <stdint.h>

typedef __bf16 bf16x8 __attribute__((ext_vector_type(8)));
typedef float f32x4 __attribute__((ext_vector_type(4)));

#define T_SEQ 4096
#define C_DIM 1024
#define H_NUM 16
#define HD 64
#define C3 3072
#define NEG_BIG (-30000.0f)

__device__ __forceinline__ unsigned short f2bf(float f) {
    uint32_t u = __builtin_bit_cast(uint32_t, f);
    u += 0x7fffu + ((u >> 16) & 1u);
    return (unsigned short)(u >> 16);
}

__device__ __forceinline__ uint32_t pk_bf16(float a, float b) {
    __hip_bfloat162 h = __float22bfloat162_rn(float2{a, b});
    uint32_t u;
    __builtin_memcpy(&u, &h, sizeof(u));
    return u;
}

__device__ __forceinline__ bf16x8 ld_bf8(const unsigned short* p) {
    return *reinterpret_cast<const bf16x8*>(p);
}

__device__ __forceinline__ void async_g2l16(const unsigned short* g, unsigned short* l) {
    __builtin_amdgcn_global_load_lds(
        (const __attribute__((address_space(1))) void*)g,
        (__attribute__((address_space(3))) void*)l, 16, 0, 0);
}

__device__ __forceinline__ void store_c(unsigned short* C, size_t idx, float v) { C[idx] = f2bf(v); }
__device__ __forceinline__ void store_c(float* C, size_t idx, float v)          { C[idx] = v; }

__device__ __forceinline__ void cvt8(const float* src, unsigned short* dst) {
    float4 f0 = *(const float4*)src;
    float4 f1 = *(const float4*)(src + 4);
    union { uint32_t w[4]; uint4 q; } t;
    t.w[0] = pk_bf16(f0.x, f0.y);
    t.w[1] = pk_bf16(f0.z, f0.w);
    t.w[2] = pk_bf16(f1.x, f1.y);
    t.w[3] = pk_bf16(f1.z, f1.w);
    *(uint4*)dst = t.q;
}

// x and w_attn fp32 -> bf16 in one launch (concatenated index space)
__global__ void cvt_xw(const float* __restrict__ x, const float* __restrict__ wa,
                       unsigned short* __restrict__ xb, unsigned short* __restrict__ wab) {
    int i = (blockIdx.x * blockDim.x + threadIdx.x) * 8;
    if (i < T_SEQ * C_DIM) cvt8(x + i, xb + i);
    else {
        int k = i - T_SEQ * C_DIM;
        if (k < C3 * C_DIM) cvt8(wa + k, wab + k);
    }
}

__global__ void cvt_f32_bf16(const float* __restrict__ src, unsigned short* __restrict__ dst, int n) {
    int i = (blockIdx.x * blockDim.x + threadIdx.x) * 8;
    if (i >= n) return;
    cvt8(src + i, dst + i);
}

// V part of qkv [T][3C] -> Vt [C][T], 64x64 tiles through padded LDS.
__global__ __launch_bounds__(256) void v_transpose(
    const unsigned short* __restrict__ qkv, unsigned short* __restrict__ Vt)
{
    __shared__ unsigned short tile[64][72];
    const int t0 = blockIdx.x * 64, c0 = blockIdx.y * 64;
    const int r = threadIdx.x >> 2, q = threadIdx.x & 3;

    const unsigned short* src = qkv + (size_t)(t0 + r) * C3 + 2 * C_DIM + c0 + q * 16;
    *(uint4*)&tile[r][q * 16]     = *(const uint4*)src;
    *(uint4*)&tile[r][q * 16 + 8] = *(const uint4*)(src + 8);
    __syncthreads();

    union { unsigned short u[16]; uint4 v[2]; } o;
    #pragma unroll
    for (int j = 0; j < 16; ++j) o.u[j] = tile[q * 16 + j][r];
    unsigned short* dst = Vt + (size_t)(c0 + r) * T_SEQ + t0 + q * 16;
    *(uint4*)dst       = o.v[0];
    *(uint4*)(dst + 8) = o.v[1];
}

// C = A @ B^T, bf16, m97 async staging. 128x128 tile, BK=32.
template <typename TC>
__global__ __launch_bounds__(256, 2) void gemm_bt(
    const unsigned short* __restrict__ A, const unsigned short* __restrict__ B,
    TC* __restrict__ C, int M, int N, int K)
{
    __shared__ __attribute__((aligned(16))) unsigned short As[128 * 32];
    __shared__ __attribute__((aligned(16))) unsigned short Bs[128 * 32];

    const int tid  = threadIdx.x;
    const int wave = tid >> 6, lane = tid & 63;
    const int quad = lane >> 4, l16 = lane & 15;
    const int wm = wave >> 1, wn = wave & 1;
    const int m0 = blockIdx.y * 128, n0 = blockIdx.x * 128;

    const int srow = wave * 32 + (lane >> 2);
    const int scol = (lane & 3) * 8;

    f32x4 acc[4][4] = {};

    for (int k0 = 0; k0 < K; k0 += 32) {
        {
            const unsigned short* ga = A + (size_t)(m0 + srow) * K + k0 + scol;
            const unsigned short* gb = B + (size_t)(n0 + srow) * K + k0 + scol;
            unsigned short* la = As + (wave * 32) * 32;
            unsigned short* lb = Bs + (wave * 32) * 32;
            async_g2l16(ga, la);
            async_g2l16(ga + (size_t)16 * K, la + 16 * 32);
            async_g2l16(gb, lb);
            async_g2l16(gb + (size_t)16 * K, lb + 16 * 32);
        }
        __syncthreads();

        bf16x8 af[4], bf[4];
        #pragma unroll
        for (int i = 0; i < 4; ++i) {
            af[i] = ld_bf8(As + (wm * 64 + i * 16 + l16) * 32 + quad * 8);
            bf[i] = ld_bf8(Bs + (wn * 64 + i * 16 + l16) * 32 + quad * 8);
        }
        #pragma unroll
        for (int mt = 0; mt < 4; ++mt)
            #pragma unroll
            for (int nt = 0; nt < 4; ++nt)
                acc[mt][nt] = __builtin_amdgcn_mfma_f32_16x16x32_bf16(
                    af[mt], bf[nt], acc[mt][nt], 0, 0, 0);
        __syncthreads();
    }

    #pragma unroll
    for (int mt = 0; mt < 4; ++mt)
        #pragma unroll
        for (int nt = 0; nt < 4; ++nt)
            #pragma unroll
            for (int r = 0; r < 4; ++r) {
                int row = m0 + wm * 64 + mt * 16 + quad * 4 + r;
                int col = n0 + wn * 64 + nt * 16 + l16;
                store_c(C, (size_t)row * N + col, acc[mt][nt][r]);
            }
}

// One flash tile, 32 q-rows/wave (2 q-subtiles), max-free softmax.
template <bool MASK>
__device__ __forceinline__ void fa7_tile(
    const unsigned short* Ksb, const unsigned short* Vsb, unsigned short* pbuf,
    const bf16x8 qf[2][2], f32x4 o[2][4], float* l_part,
    int k0, int q_abs0, int quad, int l16, int sw, int fo0, int fo1)
{
    const unsigned short* krow = Ksb + l16 * 64;
    bf16x8 kf[4][2];
    #pragma unroll
    for (int s = 0; s < 4; ++s) {
        kf[s][0] = ld_bf8(krow + s * 1024 + fo0);
        kf[s][1] = ld_bf8(krow + s * 1024 + fo1);
    }

    #pragma unroll
    for (int qs = 0; qs < 2; ++qs) {
        f32x4 st[4];
        #pragma unroll
        for (int s = 0; s < 4; ++s) {
            f32x4 z = {};
            z = __builtin_amdgcn_mfma_f32_16x16x32_bf16(kf[s][0], qf[qs][0], z, 0, 0, 0);
            st[s] = __builtin_amdgcn_mfma_f32_16x16x32_bf16(kf[s][1], qf[qs][1], z, 0, 0, 0);
        }
        float ts = 0.f;
        #pragma unroll
        for (int s = 0; s < 4; ++s)
            #pragma unroll
            for (int r = 0; r < 4; ++r) {
                float v = st[s][r];
                if (MASK) {
                    int key = k0 + s * 16 + quad * 4 + r;
                    v = (key <= q_abs0 + qs * 16) ? v : NEG_BIG;
                }
                float e = __builtin_amdgcn_exp2f(v);   // exp2(-30000) = 0
                st[s][r] = e;
                ts += e;
            }
        l_part[qs] += ts;

        unsigned short* prow = pbuf + (qs * 16 + l16) * 64;
        #pragma unroll
        for (int s = 0; s < 4; ++s) {
            int g = 2 * s + (quad >> 1);
            uint2 pk;
            pk.x = pk_bf16(st[s][0], st[s][1]);
            pk.y = pk_bf16(st[s][2], st[s][3]);
            *(uint2*)((char*)prow + (g ^ sw) * 16 + 8 * (quad & 1)) = pk;
        }
    }

    const unsigned short* vrow = Vsb + l16 * 64;
    bf16x8 vf[4][2];
    #pragma unroll
    for (int c = 0; c < 4; ++c) {
        vf[c][0] = ld_bf8(vrow + c * 1024 + fo0);
        vf[c][1] = ld_bf8(vrow + c * 1024 + fo1);
    }
    #pragma unroll
    for (int qs = 0; qs < 2; ++qs) {
        const unsigned short* prow = pbuf + (qs * 16 + l16) * 64;
        bf16x8 pf0 = ld_bf8(prow + fo0);
        bf16x8 pf1 = ld_bf8(prow + fo1);
        #pragma unroll
        for (int c = 0; c < 4; ++c) {
            o[qs][c] = __builtin_amdgcn_mfma_f32_16x16x32_bf16(vf[c][0], pf0, o[qs][c], 0, 0, 0);
            o[qs][c] = __builtin_amdgcn_mfma_f32_16x16x32_bf16(vf[c][1], pf1, o[qs][c], 0, 0, 0);
        }
    }
}

// Flash v7: 2-wave blocks (64 q-rows, 32/wave), 1024 snake-balanced blocks,
// 40KB LDS -> 4 blocks/CU (4 independent barrier domains), dbuf K/V staging,
// max-free softmax.
__global__ __launch_bounds__(128, 2) void flash_attn7(
    const unsigned short* __restrict__ qkv,
    const unsigned short* __restrict__ Vt,
    unsigned short* __restrict__ Y)
{
    __shared__ __attribute__((aligned(16))) unsigned short Ks[2][64 * 64];
    __shared__ __attribute__((aligned(16))) unsigned short Vs[2][64 * 64];
    __shared__ __attribute__((aligned(16))) unsigned short Pl[2][32 * 64];

    const int tid  = threadIdx.x;
    const int wave = tid >> 6, lane = tid & 63;
    const int quad = lane >> 4, l16 = lane & 15;

    // snake: 4 rounds x 256 slots; slot (h,j), qb = {j, 63-j, 16+j, 47-j}
    const int bi = blockIdx.x;
    const int rr = bi >> 8, ss = bi & 255;
    const int h  = ss & 15;
    const int j  = ss >> 4;
    const int qb = (rr == 0) ? j : (rr == 1) ? 63 - j : (rr == 2) ? 16 + j : 47 - j;

    const int q0w    = qb * 64 + wave * 32;
    const int q_abs0 = q0w + l16;              // qs=0 row; qs=1 adds 16
    const int sw  = l16 & 7;
    const int fo0 = (quad ^ sw) * 8;
    const int fo1 = ((quad + 4) ^ sw) * 8;

    // Q fragments (B-operand), prescaled by 0.125*log2(e); 2 q-subtiles
    bf16x8 qf[2][2];
    {
        const float QS = 0.125f * 1.44269504f;
        #pragma unroll
        for (int qs = 0; qs < 2; ++qs) {
            const unsigned short* qp =
                qkv + (size_t)(q0w + qs * 16 + l16) * C3 + h * HD + quad * 8;
            bf16x8 a = ld_bf8(qp), b = ld_bf8(qp + 32);
            #pragma unroll
            for (int i = 0; i < 8; ++i) {
                qf[qs][0][i] = (__bf16)((float)a[i] * QS);
                qf[qs][1][i] = (__bf16)((float)b[i] * QS);
            }
        }
    }

    // staging: each wave stages 32 K rows + 32 V rows (4+4 calls of 8 rows)
    const int srow = lane >> 3;
    const int schunk = (lane & 7) ^ srow;
    const unsigned short* kp =
        qkv + (size_t)(wave * 32 + srow) * C3 + C_DIM + h * HD + schunk * 8;
    const unsigned short* vp =
        Vt + (size_t)(h * HD + wave * 32 + srow) * T_SEQ + schunk * 8;
    unsigned short* lk = Ks[0] + (wave * 32) * 64;
    unsigned short* lv = Vs[0] + (wave * 32) * 64;
    const int lds_db = 64 * 64;
    const size_t kstep = (size_t)8 * C3;
    const size_t vstep = (size_t)8 * T_SEQ;

    auto stage = [&](int b) {
        #pragma unroll
        for (int jj = 0; jj < 4; ++jj) {
            async_g2l16(kp + jj * kstep, lk + b * lds_db + jj * 8 * 64);
            async_g2l16(vp + jj * vstep, lv + b * lds_db + jj * 8 * 64);
        }
    };

    f32x4 o[2][4] = {};
    float l_part[2] = {0.f, 0.f};
    unsigned short* pbuf = Pl[wave];

    const int ntiles = qb + 1;
    stage(0);
    kp += (size_t)64 * C3; vp += 64;

    for (int t = 0; t < ntiles; ++t) {
        __syncthreads();
        const int b = t & 1;
        if (t + 1 < ntiles) {
            stage(1 - b);
            kp += (size_t)64 * C3; vp += 64;
            fa7_tile<false>(Ks[b], Vs[b], pbuf, qf, o, l_part,
                            t * 64, q_abs0, quad, l16, sw, fo0, fo1);
        } else {
            fa7_tile<true>(Ks[b], Vs[b], pbuf, qf, o, l_part,
                           t * 64, q_abs0, quad, l16, sw, fo0, fo1);
        }
    }

    #pragma unroll
    for (int qs = 0; qs < 2; ++qs) {
        float l = l_part[qs];
        l += __shfl_xor(l, 16, 64);
        l += __shfl_xor(l, 32, 64);
        float inv_l = 1.f / l;
        #pragma unroll
        for (int c = 0; c < 4; ++c) {
            union { uint32_t w[2]; uint2 q; } t;
            t.w[0] = pk_bf16(o[qs][c][0] * inv_l, o[qs][c][1] * inv_l);
            t.w[1] = pk_bf16(o[qs][c][2] * inv_l, o[qs][c][3] * inv_l);
            *(uint2*)(Y + (size_t)(q_abs0 + qs * 16) * C_DIM + h * HD + c * 16 + quad * 4) = t.q;
        }
    }
}

extern "C" void kernel_launch(void* const* d_in, const int* in_sizes, int n_in,
                              void* d_out, int out_size, void* d_ws, size_t ws_size,
                              hipStream_t stream) {
    const float* x      = (const float*)d_in[0];
    const float* w_attn = (const float*)d_in[1];
    const float* w_proj = (const float*)d_in[2];
    float* out = (float*)d_out;

    unsigned short* qkv = (unsigned short*)d_ws;            // [4096,3072] bf16
    unsigned short* xb  = qkv + (size_t)T_SEQ * C3;         // [4096,1024] bf16
    unsigned short* y   = xb;                               // alias after gemm1
    unsigned short* wpb = qkv;                              // alias after flash
    unsigned short* Vt  = (unsigned short*)d_out;           // [1024][4096] bf16
    unsigned short* wab = Vt + (size_t)C_DIM * T_SEQ;       // [3072,1024] bf16

    cvt_xw<<<(T_SEQ * C_DIM + C3 * C_DIM) / 8 / 256, 256, 0, stream>>>(x, w_attn, xb, wab);

    gemm_bt<unsigned short>
        <<<dim3(C3 / 128, T_SEQ / 128), 256, 0, stream>>>(xb, wab, qkv, T_SEQ, C3, C_DIM);

    v_transpose<<<dim3(T_SEQ / 64, C_DIM / 64), 256, 0, stream>>>(qkv, Vt);

    flash_attn7<<<dim3(1024), 128, 0, stream>>>(qkv, Vt, y);

    cvt_f32_bf16<<<(C_DIM * C_DIM / 8 + 255) / 256, 256, 0, stream>>>(w_proj, wpb, C_DIM * C_DIM);
    gemm_bt<float>
        <<<dim3(C_DIM / 128, T_SEQ / 128), 256, 0, stream>>>(y, wpb, out, T_SEQ, C_DIM, C_DIM);
}